// Round 2
// baseline (75598.364 us; speedup 1.0000x reference)
//
#include <hip/hip_runtime.h>
#include <math.h>

#define BB 64
#define NN 512
#define DD 32
#define LD 33            // LDS leading dim (conflict-free for row & column access)
#define JIT 1e-5f
#define TOLF 1e-4f
#define MAXIT 10
#define MAXSWEEP 12

struct JSm {
    float cc[16], ss[16];
    int pp[16], qq[16];
};

// Parallel cyclic Jacobi eigendecomposition of symmetric 32x32 in LDS.
// A (stride LD) -> nearly diagonal (eigenvalues on diag), V -> eigenvectors (columns).
// One wave (64 threads) per matrix. Tournament ordering: 16 disjoint pairs/round, 31 rounds/sweep.
__device__ __forceinline__ void jacobi32(float* __restrict__ A, float* __restrict__ V,
                                         JSm& J, int lane) {
    // V = I
#pragma unroll
    for (int j = 0; j < 16; ++j) {
        int e = lane * 16 + j;
        int r = e >> 5, c = e & 31;
        V[r * LD + c] = (r == c) ? 1.0f : 0.0f;
    }
    __syncthreads();
    for (int sweep = 0; sweep < MAXSWEEP; ++sweep) {
        // adaptive stop: off-diagonal Frobenius^2 vs total
        float off2 = 0.0f, fro2 = 0.0f;
#pragma unroll
        for (int j = 0; j < 16; ++j) {
            int e = lane * 16 + j;
            int r = e >> 5, c = e & 31;
            float v = A[r * LD + c];
            fro2 += v * v;
            if (r != c) off2 += v * v;
        }
#pragma unroll
        for (int sh = 32; sh >= 1; sh >>= 1) {
            off2 += __shfl_xor(off2, sh, 64);
            fro2 += __shfl_xor(fro2, sh, 64);
        }
        if (off2 <= 1e-10f * fro2) break;   // off/||A|| ~ 1e-5: ample for 2.5e-2 tol
        for (int t = 0; t < 31; ++t) {
            if (lane < 16) {
                int p, q;
                if (lane == 0) { p = 31; q = t % 31; }
                else { p = (t + lane) % 31; q = (t + 31 - lane) % 31; }
                float app = A[p * LD + p];
                float aqq = A[q * LD + q];
                float apq = A[p * LD + q];
                float c, s;
                if (fabsf(apq) < 1e-30f) {
                    c = 1.0f; s = 0.0f;
                } else {
                    float tau = (aqq - app) / (2.0f * apq);
                    float tt = copysignf(1.0f, tau) / (fabsf(tau) + sqrtf(1.0f + tau * tau));
                    c = 1.0f / sqrtf(1.0f + tt * tt);
                    s = tt * c;
                }
                J.cc[lane] = c; J.ss[lane] = s; J.pp[lane] = p; J.qq[lane] = q;
            }
            __syncthreads();
            // column rotations on A and V (disjoint pairs -> no write hazards)
#pragma unroll
            for (int i = 0; i < 8; ++i) {
                int task = lane + 64 * i;      // 512 tasks: pair k, row r
                int k = task >> 5, r = task & 31;
                int p = J.pp[k], q = J.qq[k];
                float c = J.cc[k], s = J.ss[k];
                float ap = A[r * LD + p], aq = A[r * LD + q];
                A[r * LD + p] = c * ap - s * aq;
                A[r * LD + q] = s * ap + c * aq;
                float vp = V[r * LD + p], vq = V[r * LD + q];
                V[r * LD + p] = c * vp - s * vq;
                V[r * LD + q] = s * vp + c * vq;
            }
            __syncthreads();
            // row rotations on A
#pragma unroll
            for (int i = 0; i < 8; ++i) {
                int task = lane + 64 * i;
                int k = task >> 5, r = task & 31;
                int p = J.pp[k], q = J.qq[k];
                float c = J.cc[k], s = J.ss[k];
                float ap = A[p * LD + r], aq = A[q * LD + r];
                A[p * LD + r] = c * ap - s * aq;
                A[q * LD + r] = s * ap + c * aq;
            }
            __syncthreads();
        }
    }
    __syncthreads();
}

// C = A * B, all 32x32 LDS stride LD. Lane -> (row = lane>>1, 16-col chunk).
__device__ __forceinline__ void mm32(const float* __restrict__ A, const float* __restrict__ Bm,
                                     float* __restrict__ C, int lane) {
    int r = lane >> 1, cb = (lane & 1) << 4;
    float acc[16];
#pragma unroll
    for (int j = 0; j < 16; ++j) acc[j] = 0.0f;
    for (int k = 0; k < DD; ++k) {
        float a = A[r * LD + k];
        const float* Br = Bm + k * LD + cb;
#pragma unroll
        for (int j = 0; j < 16; ++j) acc[j] = fmaf(a, Br[j], acc[j]);
    }
#pragma unroll
    for (int j = 0; j < 16; ++j) C[r * LD + cb + j] = acc[j];
    __syncthreads();
}

__global__ __launch_bounds__(256) void k0_zero(float* __restrict__ G, int* __restrict__ done,
                                               float* __restrict__ norm_acc) {
    float4* Gb = (float4*)(G + blockIdx.x * 1024);
    Gb[threadIdx.x] = make_float4(0.f, 0.f, 0.f, 0.f);
    if (blockIdx.x == 0 && threadIdx.x == 0) { *done = 0; *norm_acc = 0.f; }
}

__global__ __launch_bounds__(256) void k0_mean(const float* __restrict__ X, float* __restrict__ G) {
    int blk = blockIdx.x;                 // 512 blocks: (b, chunk of 64 n)
    int b = blk >> 3, chunk = blk & 7;
    int t = threadIdx.x;
    const float4* Xb = (const float4*)(X + ((size_t)(b * NN + chunk * 64)) * 1024);
    float4 acc = make_float4(0.f, 0.f, 0.f, 0.f);
    for (int n = 0; n < 64; ++n) {
        float4 v = Xb[n * 256 + t];
        acc.x += v.x; acc.y += v.y; acc.z += v.z; acc.w += v.w;
    }
    const float inv = 1.0f / NN;
    float* Gb = G + b * 1024 + t * 4;
    atomicAdd(Gb + 0, acc.x * inv);
    atomicAdd(Gb + 1, acc.y * inv);
    atomicAdd(Gb + 2, acc.z * inv);
    atomicAdd(Gb + 3, acc.w * inv);
}

// Per-iteration: eigh(G) -> G_sqrt, G_invsqrt; zero Delta & norm accumulator.
__global__ __launch_bounds__(64) void k1_eig_g(const float* __restrict__ G,
                                               float* __restrict__ Gs, float* __restrict__ Gis,
                                               float* __restrict__ Delta, float* __restrict__ norm_acc,
                                               const int* __restrict__ done) {
    int b = blockIdx.x, lane = threadIdx.x;
    float4* Db = (float4*)(Delta + b * 1024);
#pragma unroll
    for (int j = 0; j < 4; ++j) Db[lane * 4 + j] = make_float4(0.f, 0.f, 0.f, 0.f);
    if (b == 0 && lane == 0) *norm_acc = 0.f;
    if (*done) return;
    __shared__ float sA[DD * LD], sV[DD * LD];
    __shared__ float sq[DD], siq[DD];
    __shared__ JSm J;
    const float4* Gb = (const float4*)(G + b * 1024);
#pragma unroll
    for (int j4 = 0; j4 < 4; ++j4) {
        float4 v = Gb[lane * 4 + j4];
        int e = lane * 16 + j4 * 4;
        float* d = &sA[(e >> 5) * LD + (e & 31)];
        d[0] = v.x; d[1] = v.y; d[2] = v.z; d[3] = v.w;
    }
    __syncthreads();
    if (lane < DD) sA[lane * LD + lane] += JIT;   // _safe_eigh jitter
    __syncthreads();
    jacobi32(sA, sV, J, lane);
    if (lane < DD) {
        float l = fmaxf(sA[lane * LD + lane], JIT);
        float s = sqrtf(l);
        sq[lane] = s;
        siq[lane] = 1.0f / s;
    }
    __syncthreads();
    // fused rebuild: Gs = V diag(sq) V^T, Gis = V diag(1/sq) V^T
    int r = lane >> 1, cb = (lane & 1) << 4;
    float a1[16], a2[16];
#pragma unroll
    for (int j = 0; j < 16; ++j) { a1[j] = 0.f; a2[j] = 0.f; }
    for (int k = 0; k < DD; ++k) {
        float vr = sV[r * LD + k];
        float t1 = vr * sq[k], t2 = vr * siq[k];
#pragma unroll
        for (int j = 0; j < 16; ++j) {
            float vc = sV[(cb + j) * LD + k];
            a1[j] = fmaf(t1, vc, a1[j]);
            a2[j] = fmaf(t2, vc, a2[j]);
        }
    }
    float4* Gsb = (float4*)(Gs + b * 1024);
    float4* Gisb = (float4*)(Gis + b * 1024);
#pragma unroll
    for (int j4 = 0; j4 < 4; ++j4) {
        Gsb[lane * 4 + j4]  = make_float4(a1[4*j4], a1[4*j4+1], a1[4*j4+2], a1[4*j4+3]);
        Gisb[lane * 4 + j4] = make_float4(a2[4*j4], a2[4*j4+1], a2[4*j4+2], a2[4*j4+3]);
    }
}

// The hot kernel: A = Gis X Gis; eigh(A); accumulate V log(L) V^T into Delta.
// 4096 blocks x 1 wave; each block handles 8 consecutive n for one b.
__global__ __launch_bounds__(64) void k2_log_acc(const float* __restrict__ X,
                                                 const float* __restrict__ Gis,
                                                 float* __restrict__ Delta,
                                                 const int* __restrict__ done) {
    if (*done) return;
    int lane = threadIdx.x;
    int b = blockIdx.x >> 6, chunk = blockIdx.x & 63;
    __shared__ float sG[DD * LD], sX[DD * LD], sV[DD * LD];
    __shared__ float lam[DD];
    __shared__ JSm J;
    const float4* Gb = (const float4*)(Gis + b * 1024);
#pragma unroll
    for (int j4 = 0; j4 < 4; ++j4) {
        float4 v = Gb[lane * 4 + j4];
        int e = lane * 16 + j4 * 4;
        float* d = &sG[(e >> 5) * LD + (e & 31)];
        d[0] = v.x; d[1] = v.y; d[2] = v.z; d[3] = v.w;
    }
    int r = lane >> 1, cb = (lane & 1) << 4;
    float dacc[16];
#pragma unroll
    for (int j = 0; j < 16; ++j) dacc[j] = 0.f;
    for (int nn = 0; nn < 8; ++nn) {
        int n = chunk * 8 + nn;
        const float4* Xv = (const float4*)(X + ((size_t)(b * NN + n)) * 1024);
        __syncthreads();
#pragma unroll
        for (int j4 = 0; j4 < 4; ++j4) {
            float4 v = Xv[lane * 4 + j4];
            int e = lane * 16 + j4 * 4;
            float* d = &sX[(e >> 5) * LD + (e & 31)];
            d[0] = v.x; d[1] = v.y; d[2] = v.z; d[3] = v.w;
        }
        __syncthreads();
        mm32(sG, sX, sV, lane);       // T = Gis * X   -> sV (temp)
        mm32(sV, sG, sX, lane);       // A = T * Gis   -> sX
        // symmetrize (kill fp asymmetry) + jitter
        float tmp[16];
#pragma unroll
        for (int j = 0; j < 16; ++j) {
            int e = lane * 16 + j;
            int rr = e >> 5, cc = e & 31;
            float v = 0.5f * (sX[rr * LD + cc] + sX[cc * LD + rr]);
            if (rr == cc) v = sX[rr * LD + cc] + JIT;
            tmp[j] = v;
        }
        __syncthreads();
#pragma unroll
        for (int j = 0; j < 16; ++j) {
            int e = lane * 16 + j;
            sX[(e >> 5) * LD + (e & 31)] = tmp[j];
        }
        __syncthreads();
        jacobi32(sX, sV, J, lane);
        if (lane < DD) lam[lane] = logf(fmaxf(sX[lane * LD + lane], JIT));
        __syncthreads();
        // dacc += V diag(log l) V^T  (lane's 16 outputs, kept in registers)
        for (int k = 0; k < DD; ++k) {
            float t = sV[r * LD + k] * lam[k];
#pragma unroll
            for (int j = 0; j < 16; ++j)
                dacc[j] = fmaf(t, sV[(cb + j) * LD + k], dacc[j]);
        }
        __syncthreads();
    }
    float* Db = Delta + b * 1024 + lane * 16;
#pragma unroll
    for (int j = 0; j < 16; ++j) atomicAdd(Db + j, dacc[j]);
}

// G update: Delta mean, norm, expm_taylor, M = Gs E Gs, enforce_spd, write G.
__global__ __launch_bounds__(64) void k3_update(float* __restrict__ G,
                                                const float* __restrict__ Gs,
                                                const float* __restrict__ Delta,
                                                float* __restrict__ norm_acc,
                                                const int* __restrict__ done) {
    if (*done) return;
    int b = blockIdx.x, lane = threadIdx.x;
    __shared__ float s0[DD * LD], s1[DD * LD], s2[DD * LD];
    __shared__ float lam[DD];
    __shared__ JSm J;
    int r = lane >> 1, cb = (lane & 1) << 4;
    const float4* Db = (const float4*)(Delta + b * 1024);
    float sumsq = 0.f;
    const float inv = 1.0f / NN;
#pragma unroll
    for (int j4 = 0; j4 < 4; ++j4) {
        float4 v = Db[lane * 4 + j4];
        v.x *= inv; v.y *= inv; v.z *= inv; v.w *= inv;
        sumsq += v.x * v.x + v.y * v.y + v.z * v.z + v.w * v.w;
        int e = lane * 16 + j4 * 4;
        float* d = &s0[(e >> 5) * LD + (e & 31)];
        d[0] = v.x; d[1] = v.y; d[2] = v.z; d[3] = v.w;
    }
#pragma unroll
    for (int sh = 32; sh >= 1; sh >>= 1) sumsq += __shfl_xor(sumsq, sh, 64);
    if (lane == 0) atomicAdd(norm_acc, sqrtf(sumsq));
    __syncthreads();
    // expm_taylor order 5: out = I + X + X^2/2! + ... + X^5/5!
    // X stays in s0; X^(i-1) lives in s1 (single buffer: regs -> barrier -> write).
    float outr[16];
#pragma unroll
    for (int j = 0; j < 16; ++j)
        outr[j] = ((cb + j) == r ? 1.0f : 0.0f) + s0[r * LD + cb + j];
    float fac = 1.0f;
    for (int i = 2; i <= 5; ++i) {
        fac *= (float)i;
        float acc[16];
#pragma unroll
        for (int j = 0; j < 16; ++j) acc[j] = 0.f;
        const float* Xp = (i == 2) ? s0 : s1;   // X^(i-1)
        for (int k = 0; k < DD; ++k) {
            float a = Xp[r * LD + k];
#pragma unroll
            for (int j = 0; j < 16; ++j) acc[j] = fmaf(a, s0[k * LD + cb + j], acc[j]);
        }
        float invf = 1.0f / fac;
#pragma unroll
        for (int j = 0; j < 16; ++j) outr[j] = fmaf(acc[j], invf, outr[j]);
        __syncthreads();               // all lanes done reading old s1 / s0
#pragma unroll
        for (int j = 0; j < 16; ++j) s1[r * LD + cb + j] = acc[j];   // s1 = X^i
        __syncthreads();
    }
    // E -> s0 (X no longer needed); G_sqrt -> s1
#pragma unroll
    for (int j = 0; j < 16; ++j) s0[r * LD + cb + j] = outr[j];
    const float4* Gsb = (const float4*)(Gs + b * 1024);
#pragma unroll
    for (int j4 = 0; j4 < 4; ++j4) {
        float4 v = Gsb[lane * 4 + j4];
        int e = lane * 16 + j4 * 4;
        float* d = &s1[(e >> 5) * LD + (e & 31)];
        d[0] = v.x; d[1] = v.y; d[2] = v.z; d[3] = v.w;
    }
    __syncthreads();
    mm32(s1, s0, s2, lane);   // T = Gs * E    -> s2
    mm32(s2, s1, s0, lane);   // M = T * Gs    -> s0
    // enforce_spd: symmetrize + jitter, eigh, clip, rebuild
    float tmp[16];
#pragma unroll
    for (int j = 0; j < 16; ++j) {
        int e = lane * 16 + j;
        int rr = e >> 5, cc = e & 31;
        float v = 0.5f * (s0[rr * LD + cc] + s0[cc * LD + rr]);
        if (rr == cc) v = s0[rr * LD + cc] + JIT;
        tmp[j] = v;
    }
    __syncthreads();
#pragma unroll
    for (int j = 0; j < 16; ++j) {
        int e = lane * 16 + j;
        s0[(e >> 5) * LD + (e & 31)] = tmp[j];
    }
    __syncthreads();
    jacobi32(s0, s1, J, lane);
    if (lane < DD) lam[lane] = fmaxf(s0[lane * LD + lane], JIT);
    __syncthreads();
    float g[16];
#pragma unroll
    for (int j = 0; j < 16; ++j) g[j] = 0.f;
    for (int k = 0; k < DD; ++k) {
        float t = s1[r * LD + k] * lam[k];
#pragma unroll
        for (int j = 0; j < 16; ++j) g[j] = fmaf(t, s1[(cb + j) * LD + k], g[j]);
    }
    float4* Gb = (float4*)(G + b * 1024);
#pragma unroll
    for (int j4 = 0; j4 < 4; ++j4)
        Gb[lane * 4 + j4] = make_float4(g[4*j4], g[4*j4+1], g[4*j4+2], g[4*j4+3]);
}

__global__ void k4_check(const float* __restrict__ norm_acc, int* __restrict__ done) {
    if (threadIdx.x == 0) {
        if (*norm_acc * (1.0f / BB) < TOLF) *done = 1;
    }
}

__global__ __launch_bounds__(256) void k5_out(const float* __restrict__ G, float* __restrict__ out) {
    int i = blockIdx.x * 256 + threadIdx.x;
    out[i] = G[i];
}

extern "C" void kernel_launch(void* const* d_in, const int* in_sizes, int n_in,
                              void* d_out, int out_size, void* d_ws, size_t ws_size,
                              hipStream_t stream) {
    const float* X = (const float*)d_in[0];
    float* ws = (float*)d_ws;
    float* G     = ws;                 // 65536
    float* Gs    = ws + 65536;         // 65536
    float* Gis   = ws + 2 * 65536;     // 65536
    float* Delta = ws + 3 * 65536;     // 65536
    float* norm_acc = ws + 4 * 65536;  // 1
    int*   done  = (int*)(ws + 4 * 65536 + 1);

    k0_zero<<<64, 256, 0, stream>>>(G, done, norm_acc);
    k0_mean<<<512, 256, 0, stream>>>(X, G);
    for (int it = 0; it < MAXIT; ++it) {
        k1_eig_g<<<64, 64, 0, stream>>>(G, Gs, Gis, Delta, norm_acc, done);
        k2_log_acc<<<4096, 64, 0, stream>>>(X, Gis, Delta, done);
        k3_update<<<64, 64, 0, stream>>>(G, Gs, Delta, norm_acc, done);
        k4_check<<<1, 64, 0, stream>>>(norm_acc, done);
    }
    k5_out<<<256, 256, 0, stream>>>(G, (float*)d_out);
}

// Round 3
// 35870.117 us; speedup vs baseline: 2.1076x; 2.1076x over previous
//
#include <hip/hip_runtime.h>
#include <math.h>

#define BB 64
#define NN 512
#define DD 32
#define LD 33            // old LDS leading dim (k1/k3 two-sided path)
#define LD2 36           // k2 leading dim: float4-aligned columns, conflict-free
#define JIT 1e-5f
#define TOLF 1e-4f
#define MAXIT 10
#define MAXSWEEP 12
#define MAXSWEEP1 16

struct JSm {
    float cc[16], ss[16];
    int pp[16], qq[16];
};

// ---------------- old two-sided LDS Jacobi (used by k1/k3 only; 64 matrices total, cheap) --------

__device__ __forceinline__ void jacobi32(float* __restrict__ A, float* __restrict__ V,
                                         JSm& J, int lane) {
#pragma unroll
    for (int j = 0; j < 16; ++j) {
        int e = lane * 16 + j;
        int r = e >> 5, c = e & 31;
        V[r * LD + c] = (r == c) ? 1.0f : 0.0f;
    }
    __syncthreads();
    for (int sweep = 0; sweep < MAXSWEEP; ++sweep) {
        float off2 = 0.0f, fro2 = 0.0f;
#pragma unroll
        for (int j = 0; j < 16; ++j) {
            int e = lane * 16 + j;
            int r = e >> 5, c = e & 31;
            float v = A[r * LD + c];
            fro2 += v * v;
            if (r != c) off2 += v * v;
        }
#pragma unroll
        for (int sh = 32; sh >= 1; sh >>= 1) {
            off2 += __shfl_xor(off2, sh, 64);
            fro2 += __shfl_xor(fro2, sh, 64);
        }
        if (off2 <= 1e-10f * fro2) break;
        for (int t = 0; t < 31; ++t) {
            if (lane < 16) {
                int p, q;
                if (lane == 0) { p = 31; q = t % 31; }
                else { p = (t + lane) % 31; q = (t + 31 - lane) % 31; }
                float app = A[p * LD + p];
                float aqq = A[q * LD + q];
                float apq = A[p * LD + q];
                float c, s;
                if (fabsf(apq) < 1e-30f) {
                    c = 1.0f; s = 0.0f;
                } else {
                    float tau = (aqq - app) / (2.0f * apq);
                    float tt = copysignf(1.0f, tau) / (fabsf(tau) + sqrtf(1.0f + tau * tau));
                    c = 1.0f / sqrtf(1.0f + tt * tt);
                    s = tt * c;
                }
                J.cc[lane] = c; J.ss[lane] = s; J.pp[lane] = p; J.qq[lane] = q;
            }
            __syncthreads();
#pragma unroll
            for (int i = 0; i < 8; ++i) {
                int task = lane + 64 * i;
                int k = task >> 5, r = task & 31;
                int p = J.pp[k], q = J.qq[k];
                float c = J.cc[k], s = J.ss[k];
                float ap = A[r * LD + p], aq = A[r * LD + q];
                A[r * LD + p] = c * ap - s * aq;
                A[r * LD + q] = s * ap + c * aq;
                float vp = V[r * LD + p], vq = V[r * LD + q];
                V[r * LD + p] = c * vp - s * vq;
                V[r * LD + q] = s * vp + c * vq;
            }
            __syncthreads();
#pragma unroll
            for (int i = 0; i < 8; ++i) {
                int task = lane + 64 * i;
                int k = task >> 5, r = task & 31;
                int p = J.pp[k], q = J.qq[k];
                float c = J.cc[k], s = J.ss[k];
                float ap = A[p * LD + r], aq = A[q * LD + r];
                A[p * LD + r] = c * ap - s * aq;
                A[q * LD + r] = s * ap + c * aq;
            }
            __syncthreads();
        }
    }
    __syncthreads();
}

__device__ __forceinline__ void mm32(const float* __restrict__ A, const float* __restrict__ Bm,
                                     float* __restrict__ C, int lane) {
    int r = lane >> 1, cb = (lane & 1) << 4;
    float acc[16];
#pragma unroll
    for (int j = 0; j < 16; ++j) acc[j] = 0.0f;
    for (int k = 0; k < DD; ++k) {
        float a = A[r * LD + k];
        const float* Br = Bm + k * LD + cb;
#pragma unroll
        for (int j = 0; j < 16; ++j) acc[j] = fmaf(a, Br[j], acc[j]);
    }
#pragma unroll
    for (int j = 0; j < 16; ++j) C[r * LD + cb + j] = acc[j];
    __syncthreads();
}

// ---------------- wave-synchronous helpers for k2 (single wave, no s_barrier) --------

__device__ __forceinline__ void wsync() {
    // wave-level LDS handoff: wait LDS ops retired + stop compiler motion
    __asm__ volatile("s_waitcnt lgkmcnt(0)" ::: "memory");
}

// C = A * B (32x32, stride LD2). Wave-synchronous, in-place safe (reads fully precede writes).
__device__ __forceinline__ void mm32w(const float* A, const float* B, float* C, int lane) {
    int r = lane >> 1, cb = (lane & 1) << 4;
    float acc[16];
#pragma unroll
    for (int j = 0; j < 16; ++j) acc[j] = 0.0f;
    for (int k = 0; k < DD; ++k) {
        float a = A[r * LD2 + k];
        const float4* Br = (const float4*)(B + k * LD2 + cb);
        float4 b0 = Br[0], b1 = Br[1], b2 = Br[2], b3 = Br[3];
        acc[0]  = fmaf(a, b0.x, acc[0]);  acc[1]  = fmaf(a, b0.y, acc[1]);
        acc[2]  = fmaf(a, b0.z, acc[2]);  acc[3]  = fmaf(a, b0.w, acc[3]);
        acc[4]  = fmaf(a, b1.x, acc[4]);  acc[5]  = fmaf(a, b1.y, acc[5]);
        acc[6]  = fmaf(a, b1.z, acc[6]);  acc[7]  = fmaf(a, b1.w, acc[7]);
        acc[8]  = fmaf(a, b2.x, acc[8]);  acc[9]  = fmaf(a, b2.y, acc[9]);
        acc[10] = fmaf(a, b2.z, acc[10]); acc[11] = fmaf(a, b2.w, acc[11]);
        acc[12] = fmaf(a, b3.x, acc[12]); acc[13] = fmaf(a, b3.y, acc[13]);
        acc[14] = fmaf(a, b3.z, acc[14]); acc[15] = fmaf(a, b3.w, acc[15]);
    }
    wsync();
    float4* Cr = (float4*)(C + r * LD2 + cb);
    Cr[0] = make_float4(acc[0],  acc[1],  acc[2],  acc[3]);
    Cr[1] = make_float4(acc[4],  acc[5],  acc[6],  acc[7]);
    Cr[2] = make_float4(acc[8],  acc[9],  acc[10], acc[11]);
    Cr[3] = make_float4(acc[12], acc[13], acc[14], acc[15]);
    wsync();
}

// ---------------- setup kernels ----------------

__global__ __launch_bounds__(256) void k0_zero(float* __restrict__ G, int* __restrict__ done,
                                               float* __restrict__ norm_acc) {
    float4* Gb = (float4*)(G + blockIdx.x * 1024);
    Gb[threadIdx.x] = make_float4(0.f, 0.f, 0.f, 0.f);
    if (blockIdx.x == 0 && threadIdx.x == 0) { *done = 0; *norm_acc = 0.f; }
}

__global__ __launch_bounds__(256) void k0_mean(const float* __restrict__ X, float* __restrict__ G) {
    int blk = blockIdx.x;
    int b = blk >> 3, chunk = blk & 7;
    int t = threadIdx.x;
    const float4* Xb = (const float4*)(X + ((size_t)(b * NN + chunk * 64)) * 1024);
    float4 acc = make_float4(0.f, 0.f, 0.f, 0.f);
    for (int n = 0; n < 64; ++n) {
        float4 v = Xb[n * 256 + t];
        acc.x += v.x; acc.y += v.y; acc.z += v.z; acc.w += v.w;
    }
    const float inv = 1.0f / NN;
    float* Gb = G + b * 1024 + t * 4;
    atomicAdd(Gb + 0, acc.x * inv);
    atomicAdd(Gb + 1, acc.y * inv);
    atomicAdd(Gb + 2, acc.z * inv);
    atomicAdd(Gb + 3, acc.w * inv);
}

// ---------------- k1: eigh(G) -> Gs, Gis; zero Delta/norm ----------------

__global__ __launch_bounds__(64) void k1_eig_g(const float* __restrict__ G,
                                               float* __restrict__ Gs, float* __restrict__ Gis,
                                               float* __restrict__ Delta, float* __restrict__ norm_acc,
                                               const int* __restrict__ done) {
    int b = blockIdx.x, lane = threadIdx.x;
    float4* Db = (float4*)(Delta + b * 1024);
#pragma unroll
    for (int j = 0; j < 4; ++j) Db[lane * 4 + j] = make_float4(0.f, 0.f, 0.f, 0.f);
    if (b == 0 && lane == 0) *norm_acc = 0.f;
    if (*done) return;
    __shared__ float sA[DD * LD], sV[DD * LD];
    __shared__ float sq[DD], siq[DD];
    __shared__ JSm J;
    const float4* Gb = (const float4*)(G + b * 1024);
#pragma unroll
    for (int j4 = 0; j4 < 4; ++j4) {
        float4 v = Gb[lane * 4 + j4];
        int e = lane * 16 + j4 * 4;
        float* d = &sA[(e >> 5) * LD + (e & 31)];
        d[0] = v.x; d[1] = v.y; d[2] = v.z; d[3] = v.w;
    }
    __syncthreads();
    if (lane < DD) sA[lane * LD + lane] += JIT;
    __syncthreads();
    jacobi32(sA, sV, J, lane);
    if (lane < DD) {
        float l = fmaxf(sA[lane * LD + lane], JIT);
        float s = sqrtf(l);
        sq[lane] = s;
        siq[lane] = 1.0f / s;
    }
    __syncthreads();
    int r = lane >> 1, cb = (lane & 1) << 4;
    float a1[16], a2[16];
#pragma unroll
    for (int j = 0; j < 16; ++j) { a1[j] = 0.f; a2[j] = 0.f; }
    for (int k = 0; k < DD; ++k) {
        float vr = sV[r * LD + k];
        float t1 = vr * sq[k], t2 = vr * siq[k];
#pragma unroll
        for (int j = 0; j < 16; ++j) {
            float vc = sV[(cb + j) * LD + k];
            a1[j] = fmaf(t1, vc, a1[j]);
            a2[j] = fmaf(t2, vc, a2[j]);
        }
    }
    float4* Gsb = (float4*)(Gs + b * 1024);
    float4* Gisb = (float4*)(Gis + b * 1024);
#pragma unroll
    for (int j4 = 0; j4 < 4; ++j4) {
        Gsb[lane * 4 + j4]  = make_float4(a1[4*j4], a1[4*j4+1], a1[4*j4+2], a1[4*j4+3]);
        Gisb[lane * 4 + j4] = make_float4(a2[4*j4], a2[4*j4+1], a2[4*j4+2], a2[4*j4+3]);
    }
}

// ---------------- k2: the hot kernel — register-resident one-sided Jacobi ----------------
// block = 256 (4 independent waves, same b, shared Gis tile). grid = 1024 = 4 blocks/CU exactly.
// Per wave: 8 matrices. Lane = column c (=lane&31), half h (=lane>>5): 16 rows of col c in VGPRs.
// One-sided (Hestenes): rotate cols of W (starts = A) until Gram off-diag ~0.
// Then lambda_j = ||w_j||, v_j = w_j/lambda_j, logA = W diag(log(lam)/lam^2) W^T.

__global__ __launch_bounds__(256) void k2_log_acc(const float* __restrict__ X,
                                                  const float* __restrict__ Gis,
                                                  float* __restrict__ Delta,
                                                  const int* __restrict__ done) {
    if (*done) return;
    int b = blockIdx.x >> 4, grp = blockIdx.x & 15;
    int wv = threadIdx.x >> 6, lane = threadIdx.x & 63;
    int c = lane & 31, h = lane >> 5;

    __shared__ __align__(16) float sG[DD * LD2];
    __shared__ __align__(16) float sAall[4][DD * LD2];
    __shared__ float sT[4][DD];
    float* sA = sAall[wv];
    float* sTw = sT[wv];

    // cooperative load Gis[b] -> sG (stride LD2)
    {
        int t = threadIdx.x;
        float4 v = ((const float4*)(Gis + b * 1024))[t];
        int e = t * 4;
        *((float4*)&sG[(e >> 5) * LD2 + (e & 31)]) = v;
    }
    __syncthreads();   // only block-wide barrier in this kernel

    int r = lane >> 1, cb = (lane & 1) << 4;
    float dacc[16];
#pragma unroll
    for (int j = 0; j < 16; ++j) dacc[j] = 0.f;

#pragma unroll 1
    for (int nn = 0; nn < 8; ++nn) {
        int n = grp * 32 + wv * 8 + nn;
        // stage X[b,n] -> sA
        {
            const float4* Xv = (const float4*)(X + ((size_t)(b * NN + n)) * 1024);
#pragma unroll
            for (int j4 = 0; j4 < 4; ++j4) {
                float4 v = Xv[lane * 4 + j4];
                int e = lane * 16 + j4 * 4;
                *((float4*)&sA[(e >> 5) * LD2 + (e & 31)]) = v;
            }
        }
        wsync();
        mm32w(sG, sA, sA, lane);      // T = Gis * X      (in place)
        mm32w(sA, sG, sA, lane);      // A = T * Gis      (in place)

        // extract column c (rows 16h..16h+15) with symmetrize + jitter
        float a[16];
        {
            const float4* cp = (const float4*)&sA[c * LD2 + 16 * h];
            float4 t0 = cp[0], t1 = cp[1], t2 = cp[2], t3 = cp[3];
            float tr[16] = { t0.x,t0.y,t0.z,t0.w, t1.x,t1.y,t1.z,t1.w,
                             t2.x,t2.y,t2.z,t2.w, t3.x,t3.y,t3.z,t3.w };
#pragma unroll
            for (int i = 0; i < 16; ++i) {
                int row = 16 * h + i;
                float v = 0.5f * (sA[row * LD2 + c] + tr[i]);
                if (row == c) v = tr[i] + JIT;
                a[i] = v;
            }
        }

        // one-sided Jacobi sweeps, XOR ordering
        float prevmax = 1e30f;
#pragma unroll 1
        for (int sweep = 0; sweep < MAXSWEEP1; ++sweep) {
            float maxrel = 0.f;
#pragma unroll 1
            for (int m = 1; m < 32; ++m) {
                float pa[16];
#pragma unroll
                for (int i = 0; i < 16; ++i) pa[i] = __shfl_xor(a[i], m, 64);
                float gs = 0.f, gc = 0.f;
#pragma unroll
                for (int i = 0; i < 16; ++i) {
                    gs = fmaf(a[i], a[i], gs);
                    gc = fmaf(a[i], pa[i], gc);
                }
                gs += __shfl_xor(gs, 32, 64);
                gc += __shfl_xor(gc, 32, 64);
                float gp = __shfl_xor(gs, m, 64);
                int pc = c ^ m;
                bool isP = c < pc;
                float gpp = isP ? gs : gp;
                float gqq = isP ? gp : gs;
                float rel = (gc * gc) / (gpp * gqq);
                maxrel = fmaxf(maxrel, rel);
                if (rel > 1e-24f) {
                    float tau = (gqq - gpp) / (2.f * gc);
                    float tt = copysignf(1.f, tau) / (fabsf(tau) + sqrtf(fmaf(tau, tau, 1.f)));
                    float cs = 1.f / sqrtf(fmaf(tt, tt, 1.f));
                    float sn = tt * cs;
                    if (isP) {
#pragma unroll
                        for (int i = 0; i < 16; ++i) a[i] = fmaf(-sn, pa[i], cs * a[i]);
                    } else {
#pragma unroll
                        for (int i = 0; i < 16; ++i) a[i] = fmaf(sn, pa[i], cs * a[i]);
                    }
                }
            }
#pragma unroll
            for (int sh = 1; sh <= 32; sh <<= 1)
                maxrel = fmaxf(maxrel, __shfl_xor(maxrel, sh, 64));
            if (maxrel < 1e-10f) break;
            if (sweep >= 8 && maxrel > 0.25f * prevmax) break;  // fp32 floor stagnation
            prevmax = maxrel;
        }

        // eigen extraction: lambda^2 = ||w||^2, t_k = log(lam)/lam^2
        float gs2 = 0.f;
#pragma unroll
        for (int i = 0; i < 16; ++i) gs2 = fmaf(a[i], a[i], gs2);
        gs2 += __shfl_xor(gs2, 32, 64);
        float lam = sqrtf(gs2);
        float tk = logf(fmaxf(lam, JIT)) / gs2;

        // write W^T (col c contiguous) + t, then rebuild logA into dacc
        {
            float4* wp = (float4*)&sA[c * LD2 + 16 * h];
            wp[0] = make_float4(a[0],  a[1],  a[2],  a[3]);
            wp[1] = make_float4(a[4],  a[5],  a[6],  a[7]);
            wp[2] = make_float4(a[8],  a[9],  a[10], a[11]);
            wp[3] = make_float4(a[12], a[13], a[14], a[15]);
            if (h == 0) sTw[c] = tk;
        }
        wsync();
        for (int k = 0; k < DD; ++k) {
            float t1 = sA[k * LD2 + r] * sTw[k];
            const float4* Wr = (const float4*)&sA[k * LD2 + cb];
            float4 w0 = Wr[0], w1 = Wr[1], w2 = Wr[2], w3 = Wr[3];
            dacc[0]  = fmaf(t1, w0.x, dacc[0]);  dacc[1]  = fmaf(t1, w0.y, dacc[1]);
            dacc[2]  = fmaf(t1, w0.z, dacc[2]);  dacc[3]  = fmaf(t1, w0.w, dacc[3]);
            dacc[4]  = fmaf(t1, w1.x, dacc[4]);  dacc[5]  = fmaf(t1, w1.y, dacc[5]);
            dacc[6]  = fmaf(t1, w1.z, dacc[6]);  dacc[7]  = fmaf(t1, w1.w, dacc[7]);
            dacc[8]  = fmaf(t1, w2.x, dacc[8]);  dacc[9]  = fmaf(t1, w2.y, dacc[9]);
            dacc[10] = fmaf(t1, w2.z, dacc[10]); dacc[11] = fmaf(t1, w2.w, dacc[11]);
            dacc[12] = fmaf(t1, w3.x, dacc[12]); dacc[13] = fmaf(t1, w3.y, dacc[13]);
            dacc[14] = fmaf(t1, w3.z, dacc[14]); dacc[15] = fmaf(t1, w3.w, dacc[15]);
        }
        wsync();   // before next nn overwrites sA
    }

    float* Db = Delta + b * 1024 + lane * 16;
#pragma unroll
    for (int j = 0; j < 16; ++j) atomicAdd(Db + j, dacc[j]);
}

// ---------------- k3: Delta mean/norm, expm_taylor, M = Gs E Gs, enforce_spd ----------------

__global__ __launch_bounds__(64) void k3_update(float* __restrict__ G,
                                                const float* __restrict__ Gs,
                                                const float* __restrict__ Delta,
                                                float* __restrict__ norm_acc,
                                                const int* __restrict__ done) {
    if (*done) return;
    int b = blockIdx.x, lane = threadIdx.x;
    __shared__ float s0[DD * LD], s1[DD * LD], s2[DD * LD];
    __shared__ float lam[DD];
    __shared__ JSm J;
    int r = lane >> 1, cb = (lane & 1) << 4;
    const float4* Db = (const float4*)(Delta + b * 1024);
    float sumsq = 0.f;
    const float inv = 1.0f / NN;
#pragma unroll
    for (int j4 = 0; j4 < 4; ++j4) {
        float4 v = Db[lane * 4 + j4];
        v.x *= inv; v.y *= inv; v.z *= inv; v.w *= inv;
        sumsq += v.x * v.x + v.y * v.y + v.z * v.z + v.w * v.w;
        int e = lane * 16 + j4 * 4;
        float* d = &s0[(e >> 5) * LD + (e & 31)];
        d[0] = v.x; d[1] = v.y; d[2] = v.z; d[3] = v.w;
    }
#pragma unroll
    for (int sh = 32; sh >= 1; sh >>= 1) sumsq += __shfl_xor(sumsq, sh, 64);
    if (lane == 0) atomicAdd(norm_acc, sqrtf(sumsq));
    __syncthreads();
    float outr[16];
#pragma unroll
    for (int j = 0; j < 16; ++j)
        outr[j] = ((cb + j) == r ? 1.0f : 0.0f) + s0[r * LD + cb + j];
    float fac = 1.0f;
    for (int i = 2; i <= 5; ++i) {
        fac *= (float)i;
        float acc[16];
#pragma unroll
        for (int j = 0; j < 16; ++j) acc[j] = 0.f;
        const float* Xp = (i == 2) ? s0 : s1;
        for (int k = 0; k < DD; ++k) {
            float a = Xp[r * LD + k];
#pragma unroll
            for (int j = 0; j < 16; ++j) acc[j] = fmaf(a, s0[k * LD + cb + j], acc[j]);
        }
        float invf = 1.0f / fac;
#pragma unroll
        for (int j = 0; j < 16; ++j) outr[j] = fmaf(acc[j], invf, outr[j]);
        __syncthreads();
#pragma unroll
        for (int j = 0; j < 16; ++j) s1[r * LD + cb + j] = acc[j];
        __syncthreads();
    }
#pragma unroll
    for (int j = 0; j < 16; ++j) s0[r * LD + cb + j] = outr[j];
    const float4* Gsb = (const float4*)(Gs + b * 1024);
#pragma unroll
    for (int j4 = 0; j4 < 4; ++j4) {
        float4 v = Gsb[lane * 4 + j4];
        int e = lane * 16 + j4 * 4;
        float* d = &s1[(e >> 5) * LD + (e & 31)];
        d[0] = v.x; d[1] = v.y; d[2] = v.z; d[3] = v.w;
    }
    __syncthreads();
    mm32(s1, s0, s2, lane);
    mm32(s2, s1, s0, lane);
    float tmp[16];
#pragma unroll
    for (int j = 0; j < 16; ++j) {
        int e = lane * 16 + j;
        int rr = e >> 5, cc = e & 31;
        float v = 0.5f * (s0[rr * LD + cc] + s0[cc * LD + rr]);
        if (rr == cc) v = s0[rr * LD + cc] + JIT;
        tmp[j] = v;
    }
    __syncthreads();
#pragma unroll
    for (int j = 0; j < 16; ++j) {
        int e = lane * 16 + j;
        s0[(e >> 5) * LD + (e & 31)] = tmp[j];
    }
    __syncthreads();
    jacobi32(s0, s1, J, lane);
    if (lane < DD) lam[lane] = fmaxf(s0[lane * LD + lane], JIT);
    __syncthreads();
    float g[16];
#pragma unroll
    for (int j = 0; j < 16; ++j) g[j] = 0.f;
    for (int k = 0; k < DD; ++k) {
        float t = s1[r * LD + k] * lam[k];
#pragma unroll
        for (int j = 0; j < 16; ++j) g[j] = fmaf(t, s1[(cb + j) * LD + k], g[j]);
    }
    float4* Gb = (float4*)(G + b * 1024);
#pragma unroll
    for (int j4 = 0; j4 < 4; ++j4)
        Gb[lane * 4 + j4] = make_float4(g[4*j4], g[4*j4+1], g[4*j4+2], g[4*j4+3]);
}

__global__ void k4_check(const float* __restrict__ norm_acc, int* __restrict__ done) {
    if (threadIdx.x == 0) {
        if (*norm_acc * (1.0f / BB) < TOLF) *done = 1;
    }
}

__global__ __launch_bounds__(256) void k5_out(const float* __restrict__ G, float* __restrict__ out) {
    int i = blockIdx.x * 256 + threadIdx.x;
    out[i] = G[i];
}

extern "C" void kernel_launch(void* const* d_in, const int* in_sizes, int n_in,
                              void* d_out, int out_size, void* d_ws, size_t ws_size,
                              hipStream_t stream) {
    const float* X = (const float*)d_in[0];
    float* ws = (float*)d_ws;
    float* G     = ws;
    float* Gs    = ws + 65536;
    float* Gis   = ws + 2 * 65536;
    float* Delta = ws + 3 * 65536;
    float* norm_acc = ws + 4 * 65536;
    int*   done  = (int*)(ws + 4 * 65536 + 1);

    k0_zero<<<64, 256, 0, stream>>>(G, done, norm_acc);
    k0_mean<<<512, 256, 0, stream>>>(X, G);
    for (int it = 0; it < MAXIT; ++it) {
        k1_eig_g<<<64, 64, 0, stream>>>(G, Gs, Gis, Delta, norm_acc, done);
        k2_log_acc<<<1024, 256, 0, stream>>>(X, Gis, Delta, done);
        k3_update<<<64, 64, 0, stream>>>(G, Gs, Delta, norm_acc, done);
        k4_check<<<1, 64, 0, stream>>>(norm_acc, done);
    }
    k5_out<<<256, 256, 0, stream>>>(G, (float*)d_out);
}

// Round 4
// 8170.379 us; speedup vs baseline: 9.2527x; 4.3903x over previous
//
#include <hip/hip_runtime.h>
#include <math.h>

#define BB 64
#define NN 512
#define DD 32
#define LD2 36           // LDS leading dim: float4-aligned columns, conflict-free-ish
#define JIT 1e-5f
#define TOLF 1e-4f
#define MAXIT 10

// lane-pull via LDS permute unit; addr = src_lane<<2
__device__ __forceinline__ float bpf(int addr, float v) {
    return __int_as_float(__builtin_amdgcn_ds_bpermute(addr, __float_as_int(v)));
}

__device__ __forceinline__ void wsync() {
    // wave-level LDS handoff (single-wave or per-wave-buffer use only)
    __asm__ volatile("s_waitcnt lgkmcnt(0)" ::: "memory");
}

// ---------------- register-resident one-sided (Hestenes) Jacobi ----------------
// Lane = (col c = lane&31, half h = lane>>5) holds 16 rows of column c of W in a[16].
// XOR-cyclic sweeps: pair {c, c^m}, m=1..31. After convergence w_j = lam_j v_j.
__device__ __forceinline__ void jac1(float a[16], int aself, int a32, int c,
                                     int maxsweep, float thr) {
#pragma unroll 1
    for (int sweep = 0; sweep < maxsweep; ++sweep) {
        float maxrel = 0.f;
#pragma unroll 1
        for (int m = 1; m < 32; ++m) {
            int am = aself ^ (m << 2);
            float pa[16];
#pragma unroll
            for (int i = 0; i < 16; ++i) pa[i] = bpf(am, a[i]);
            float gs = 0.f, gc = 0.f;
#pragma unroll
            for (int i = 0; i < 16; ++i) {
                gs = fmaf(a[i], a[i], gs);
                gc = fmaf(a[i], pa[i], gc);
            }
            gs += bpf(a32, gs);
            gc += bpf(a32, gc);
            float gp = bpf(am, gs);
            bool isP = c < (c ^ m);
            float gpp = isP ? gs : gp;
            float gqq = isP ? gp : gs;
            float rel = gc * gc * __builtin_amdgcn_rcpf(gpp * gqq);
            maxrel = fmaxf(maxrel, rel);
            float tau = (gqq - gpp) * (0.5f * __builtin_amdgcn_rcpf(gc));
            float den = fabsf(tau) + __builtin_amdgcn_sqrtf(fmaf(tau, tau, 1.f));
            float tt  = copysignf(__builtin_amdgcn_rcpf(den), tau);
            float cs  = __builtin_amdgcn_rsqf(fmaf(tt, tt, 1.f));
            float sn  = tt * cs;
            bool doit = rel > 1e-24f;          // also guards NaN from gc==0
            cs = doit ? cs : 1.f;
            sn = doit ? sn : 0.f;
            float sg = isP ? -sn : sn;
#pragma unroll
            for (int i = 0; i < 16; ++i) a[i] = fmaf(sg, pa[i], cs * a[i]);
        }
#pragma unroll
        for (int sh = 1; sh <= 32; sh <<= 1)
            maxrel = fmaxf(maxrel, bpf(aself ^ (sh << 2), maxrel));
        if (maxrel < thr) break;
    }
}

// C = A * B (32x32, stride LD2). Wave-synchronous, in-place safe for a single wave.
__device__ __forceinline__ void mm32w(const float* A, const float* B, float* C, int lane) {
    int r = lane >> 1, cb = (lane & 1) << 4;
    float acc[16];
#pragma unroll
    for (int j = 0; j < 16; ++j) acc[j] = 0.0f;
    for (int k = 0; k < DD; ++k) {
        float a = A[r * LD2 + k];
        const float4* Br = (const float4*)(B + k * LD2 + cb);
        float4 b0 = Br[0], b1 = Br[1], b2 = Br[2], b3 = Br[3];
        acc[0]  = fmaf(a, b0.x, acc[0]);  acc[1]  = fmaf(a, b0.y, acc[1]);
        acc[2]  = fmaf(a, b0.z, acc[2]);  acc[3]  = fmaf(a, b0.w, acc[3]);
        acc[4]  = fmaf(a, b1.x, acc[4]);  acc[5]  = fmaf(a, b1.y, acc[5]);
        acc[6]  = fmaf(a, b1.z, acc[6]);  acc[7]  = fmaf(a, b1.w, acc[7]);
        acc[8]  = fmaf(a, b2.x, acc[8]);  acc[9]  = fmaf(a, b2.y, acc[9]);
        acc[10] = fmaf(a, b2.z, acc[10]); acc[11] = fmaf(a, b2.w, acc[11]);
        acc[12] = fmaf(a, b3.x, acc[12]); acc[13] = fmaf(a, b3.y, acc[13]);
        acc[14] = fmaf(a, b3.z, acc[14]); acc[15] = fmaf(a, b3.w, acc[15]);
    }
    wsync();
    float4* Cr = (float4*)(C + r * LD2 + cb);
    Cr[0] = make_float4(acc[0],  acc[1],  acc[2],  acc[3]);
    Cr[1] = make_float4(acc[4],  acc[5],  acc[6],  acc[7]);
    Cr[2] = make_float4(acc[8],  acc[9],  acc[10], acc[11]);
    Cr[3] = make_float4(acc[12], acc[13], acc[14], acc[15]);
    wsync();
}

// ---------------- setup ----------------

__global__ __launch_bounds__(256) void k0_zero(float* __restrict__ G, int* __restrict__ done,
                                               float* __restrict__ norm_acc) {
    float4* Gb = (float4*)(G + blockIdx.x * 1024);
    Gb[threadIdx.x] = make_float4(0.f, 0.f, 0.f, 0.f);
    if (blockIdx.x == 0 && threadIdx.x == 0) { *done = 0; *norm_acc = 0.f; }
}

__global__ __launch_bounds__(256) void k0_mean(const float* __restrict__ X, float* __restrict__ G) {
    int blk = blockIdx.x;
    int b = blk >> 3, chunk = blk & 7;
    int t = threadIdx.x;
    const float4* Xb = (const float4*)(X + ((size_t)(b * NN + chunk * 64)) * 1024);
    float4 acc = make_float4(0.f, 0.f, 0.f, 0.f);
    for (int n = 0; n < 64; ++n) {
        float4 v = Xb[n * 256 + t];
        acc.x += v.x; acc.y += v.y; acc.z += v.z; acc.w += v.w;
    }
    const float inv = 1.0f / NN;
    float* Gb = G + b * 1024 + t * 4;
    atomicAdd(Gb + 0, acc.x * inv);
    atomicAdd(Gb + 1, acc.y * inv);
    atomicAdd(Gb + 2, acc.z * inv);
    atomicAdd(Gb + 3, acc.w * inv);
}

// ---------------- k1: eigh(G) -> Gs, Gis (one wave per b) ----------------

__global__ __launch_bounds__(64) void k1_eig_g(const float* __restrict__ G,
                                               float* __restrict__ Gs, float* __restrict__ Gis,
                                               float* __restrict__ norm_acc,
                                               const int* __restrict__ done) {
    int b = blockIdx.x, lane = threadIdx.x;
    if (b == 0 && lane == 0) *norm_acc = 0.f;
    if (*done) return;
    int c = lane & 31, h = lane >> 5;
    int aself = lane << 2, a32 = aself ^ 128;
    int r = lane >> 1, cb = (lane & 1) << 4;
    __shared__ __align__(16) float sW[DD * LD2];
    __shared__ float sc1[DD], sc2[DD];

    // column c of G (= row c, symmetric), rows 16h..16h+15
    float a[16];
    {
        const float4* Gc = (const float4*)(G + b * 1024 + c * 32 + 16 * h);
        float4 v0 = Gc[0], v1 = Gc[1], v2 = Gc[2], v3 = Gc[3];
        a[0]=v0.x; a[1]=v0.y; a[2]=v0.z; a[3]=v0.w;
        a[4]=v1.x; a[5]=v1.y; a[6]=v1.z; a[7]=v1.w;
        a[8]=v2.x; a[9]=v2.y; a[10]=v2.z; a[11]=v2.w;
        a[12]=v3.x; a[13]=v3.y; a[14]=v3.z; a[15]=v3.w;
#pragma unroll
        for (int i = 0; i < 16; ++i)
            if (16 * h + i == c) a[i] += JIT;   // _safe_eigh jitter
    }
    jac1(a, aself, a32, c, 10, 1e-12f);
    float gs2 = 0.f;
#pragma unroll
    for (int i = 0; i < 16; ++i) gs2 = fmaf(a[i], a[i], gs2);
    gs2 += bpf(a32, gs2);
    float l  = __builtin_amdgcn_sqrtf(gs2);
    float lc = fmaxf(l, JIT);
    float ig = __builtin_amdgcn_rcpf(gs2);
    float c1 = __builtin_amdgcn_sqrtf(lc) * ig;   // sqrt(clip(lam)) / lam^2
    float c2 = __builtin_amdgcn_rsqf(lc) * ig;    // 1/sqrt(clip(lam)) / lam^2
    {
        float4* wp = (float4*)&sW[c * LD2 + 16 * h];
        wp[0] = make_float4(a[0],  a[1],  a[2],  a[3]);
        wp[1] = make_float4(a[4],  a[5],  a[6],  a[7]);
        wp[2] = make_float4(a[8],  a[9],  a[10], a[11]);
        wp[3] = make_float4(a[12], a[13], a[14], a[15]);
        if (h == 0) { sc1[c] = c1; sc2[c] = c2; }
    }
    wsync();
    float a1[16], a2[16];
#pragma unroll
    for (int j = 0; j < 16; ++j) { a1[j] = 0.f; a2[j] = 0.f; }
    for (int k = 0; k < DD; ++k) {
        float wr = sW[k * LD2 + r];
        float t1 = wr * sc1[k], t2 = wr * sc2[k];
        const float4* Wc = (const float4*)&sW[k * LD2 + cb];
        float4 w0 = Wc[0], w1 = Wc[1], w2 = Wc[2], w3 = Wc[3];
        a1[0]  = fmaf(t1, w0.x, a1[0]);  a2[0]  = fmaf(t2, w0.x, a2[0]);
        a1[1]  = fmaf(t1, w0.y, a1[1]);  a2[1]  = fmaf(t2, w0.y, a2[1]);
        a1[2]  = fmaf(t1, w0.z, a1[2]);  a2[2]  = fmaf(t2, w0.z, a2[2]);
        a1[3]  = fmaf(t1, w0.w, a1[3]);  a2[3]  = fmaf(t2, w0.w, a2[3]);
        a1[4]  = fmaf(t1, w1.x, a1[4]);  a2[4]  = fmaf(t2, w1.x, a2[4]);
        a1[5]  = fmaf(t1, w1.y, a1[5]);  a2[5]  = fmaf(t2, w1.y, a2[5]);
        a1[6]  = fmaf(t1, w1.z, a1[6]);  a2[6]  = fmaf(t2, w1.z, a2[6]);
        a1[7]  = fmaf(t1, w1.w, a1[7]);  a2[7]  = fmaf(t2, w1.w, a2[7]);
        a1[8]  = fmaf(t1, w2.x, a1[8]);  a2[8]  = fmaf(t2, w2.x, a2[8]);
        a1[9]  = fmaf(t1, w2.y, a1[9]);  a2[9]  = fmaf(t2, w2.y, a2[9]);
        a1[10] = fmaf(t1, w2.z, a1[10]); a2[10] = fmaf(t2, w2.z, a2[10]);
        a1[11] = fmaf(t1, w2.w, a1[11]); a2[11] = fmaf(t2, w2.w, a2[11]);
        a1[12] = fmaf(t1, w3.x, a1[12]); a2[12] = fmaf(t2, w3.x, a2[12]);
        a1[13] = fmaf(t1, w3.y, a1[13]); a2[13] = fmaf(t2, w3.y, a2[13]);
        a1[14] = fmaf(t1, w3.z, a1[14]); a2[14] = fmaf(t2, w3.z, a2[14]);
        a1[15] = fmaf(t1, w3.w, a1[15]); a2[15] = fmaf(t2, w3.w, a2[15]);
    }
    float4* Gsb  = (float4*)(Gs  + b * 1024 + lane * 16);
    float4* Gisb = (float4*)(Gis + b * 1024 + lane * 16);
#pragma unroll
    for (int j4 = 0; j4 < 4; ++j4) {
        Gsb[j4]  = make_float4(a1[4*j4], a1[4*j4+1], a1[4*j4+2], a1[4*j4+3]);
        Gisb[j4] = make_float4(a2[4*j4], a2[4*j4+1], a2[4*j4+2], a2[4*j4+3]);
    }
}

// ---------------- k2: hot kernel ----------------
// 1024 blocks x 4 waves; block bx: b = bx>>4, grp = bx&15; wave handles 8 matrices.
// Per matrix: A = Gis X Gis (LDS), one-sided Jacobi in regs, logA accumulated into dacc.
// Block-level LDS reduction -> one 1024-float partial store per block (no atomics).

__global__ __launch_bounds__(256) void k2_log_acc(const float* __restrict__ X,
                                                  const float* __restrict__ Gis,
                                                  float* __restrict__ Part,
                                                  const int* __restrict__ done) {
    if (*done) return;
    int b = blockIdx.x >> 4, grp = blockIdx.x & 15;
    int wv = threadIdx.x >> 6, lane = threadIdx.x & 63;
    int c = lane & 31, h = lane >> 5;
    int aself = lane << 2, a32 = aself ^ 128;

    __shared__ __align__(16) float sG[DD * LD2];
    __shared__ __align__(16) float sAall[4][DD * LD2];
    __shared__ float sT[4][DD];
    float* sA = sAall[wv];
    float* sTw = sT[wv];

    {
        int t = threadIdx.x;
        float4 v = ((const float4*)(Gis + b * 1024))[t];
        int e = t * 4;
        *((float4*)&sG[(e >> 5) * LD2 + (e & 31)]) = v;
    }
    __syncthreads();

    int r = lane >> 1, cb = (lane & 1) << 4;
    float dacc[16];
#pragma unroll
    for (int j = 0; j < 16; ++j) dacc[j] = 0.f;

#pragma unroll 1
    for (int nn = 0; nn < 8; ++nn) {
        int n = grp * 32 + wv * 8 + nn;
        {
            const float4* Xv = (const float4*)(X + ((size_t)(b * NN + n)) * 1024);
#pragma unroll
            for (int j4 = 0; j4 < 4; ++j4) {
                float4 v = Xv[lane * 4 + j4];
                int e = lane * 16 + j4 * 4;
                *((float4*)&sA[(e >> 5) * LD2 + (e & 31)]) = v;
            }
        }
        wsync();
        mm32w(sG, sA, sA, lane);      // T = Gis * X
        mm32w(sA, sG, sA, lane);      // A = T * Gis

        float a[16];
        {
            const float4* cp = (const float4*)&sA[c * LD2 + 16 * h];
            float4 t0 = cp[0], t1 = cp[1], t2 = cp[2], t3 = cp[3];
            float tr[16] = { t0.x,t0.y,t0.z,t0.w, t1.x,t1.y,t1.z,t1.w,
                             t2.x,t2.y,t2.z,t2.w, t3.x,t3.y,t3.z,t3.w };
#pragma unroll
            for (int i = 0; i < 16; ++i) {
                int row = 16 * h + i;
                float v = 0.5f * (sA[row * LD2 + c] + tr[i]);
                if (row == c) v = tr[i] + JIT;
                a[i] = v;
            }
        }

        jac1(a, aself, a32, c, 8, 3e-10f);

        float gs2 = 0.f;
#pragma unroll
        for (int i = 0; i < 16; ++i) gs2 = fmaf(a[i], a[i], gs2);
        gs2 += bpf(a32, gs2);
        float gs2c = fmaxf(gs2, JIT * JIT);
        // log(clip(lam)) / lam^2 with lam = sqrt(gs2)
        float tk = 0.5f * logf(gs2c) * __builtin_amdgcn_rcpf(gs2);

        wsync();
        {
            float4* wp = (float4*)&sA[c * LD2 + 16 * h];
            wp[0] = make_float4(a[0],  a[1],  a[2],  a[3]);
            wp[1] = make_float4(a[4],  a[5],  a[6],  a[7]);
            wp[2] = make_float4(a[8],  a[9],  a[10], a[11]);
            wp[3] = make_float4(a[12], a[13], a[14], a[15]);
            if (h == 0) sTw[c] = tk;
        }
        wsync();
        for (int k = 0; k < DD; ++k) {
            float t1 = sA[k * LD2 + r] * sTw[k];
            const float4* Wr = (const float4*)&sA[k * LD2 + cb];
            float4 w0 = Wr[0], w1 = Wr[1], w2 = Wr[2], w3 = Wr[3];
            dacc[0]  = fmaf(t1, w0.x, dacc[0]);  dacc[1]  = fmaf(t1, w0.y, dacc[1]);
            dacc[2]  = fmaf(t1, w0.z, dacc[2]);  dacc[3]  = fmaf(t1, w0.w, dacc[3]);
            dacc[4]  = fmaf(t1, w1.x, dacc[4]);  dacc[5]  = fmaf(t1, w1.y, dacc[5]);
            dacc[6]  = fmaf(t1, w1.z, dacc[6]);  dacc[7]  = fmaf(t1, w1.w, dacc[7]);
            dacc[8]  = fmaf(t1, w2.x, dacc[8]);  dacc[9]  = fmaf(t1, w2.y, dacc[9]);
            dacc[10] = fmaf(t1, w2.z, dacc[10]); dacc[11] = fmaf(t1, w2.w, dacc[11]);
            dacc[12] = fmaf(t1, w3.x, dacc[12]); dacc[13] = fmaf(t1, w3.y, dacc[13]);
            dacc[14] = fmaf(t1, w3.z, dacc[14]); dacc[15] = fmaf(t1, w3.w, dacc[15]);
        }
        wsync();
    }

    // block reduction: dacc layout flat = lane*16+j (== row r, col cb+j)
    {
        float4* fp = (float4*)&sA[lane * 16];
        fp[0] = make_float4(dacc[0],  dacc[1],  dacc[2],  dacc[3]);
        fp[1] = make_float4(dacc[4],  dacc[5],  dacc[6],  dacc[7]);
        fp[2] = make_float4(dacc[8],  dacc[9],  dacc[10], dacc[11]);
        fp[3] = make_float4(dacc[12], dacc[13], dacc[14], dacc[15]);
    }
    __syncthreads();
    {
        int t = threadIdx.x;
        float4 s0 = ((float4*)sAall[0])[t];
        float4 s1 = ((float4*)sAall[1])[t];
        float4 s2 = ((float4*)sAall[2])[t];
        float4 s3 = ((float4*)sAall[3])[t];
        float4 s;
        s.x = (s0.x + s1.x) + (s2.x + s3.x);
        s.y = (s0.y + s1.y) + (s2.y + s3.y);
        s.z = (s0.z + s1.z) + (s2.z + s3.z);
        s.w = (s0.w + s1.w) + (s2.w + s3.w);
        ((float4*)(Part + (size_t)blockIdx.x * 1024))[t] = s;
    }
}

// ---------------- k3: sum partials, norm, expm_taylor, M = Gs E Gs, enforce_spd ----------------

__global__ __launch_bounds__(64) void k3_update(float* __restrict__ G,
                                                const float* __restrict__ Gs,
                                                const float* __restrict__ Part,
                                                float* __restrict__ norm_acc,
                                                const int* __restrict__ done) {
    if (*done) return;
    int b = blockIdx.x, lane = threadIdx.x;
    int c = lane & 31, h = lane >> 5;
    int aself = lane << 2, a32 = aself ^ 128;
    int r = lane >> 1, cb = (lane & 1) << 4;
    __shared__ __align__(16) float s0[DD * LD2], s1[DD * LD2], s2[DD * LD2];
    __shared__ float sc[DD];

    // Delta = sum of 16 partials / NN   (flat lane*16+j = (r, cb+j))
    float d[16];
#pragma unroll
    for (int j = 0; j < 16; ++j) d[j] = 0.f;
#pragma unroll 1
    for (int g = 0; g < 16; ++g) {
        const float4* P = (const float4*)(Part + (size_t)(b * 16 + g) * 1024 + lane * 16);
        float4 p0 = P[0], p1 = P[1], p2 = P[2], p3 = P[3];
        d[0]+=p0.x; d[1]+=p0.y; d[2]+=p0.z; d[3]+=p0.w;
        d[4]+=p1.x; d[5]+=p1.y; d[6]+=p1.z; d[7]+=p1.w;
        d[8]+=p2.x; d[9]+=p2.y; d[10]+=p2.z; d[11]+=p2.w;
        d[12]+=p3.x; d[13]+=p3.y; d[14]+=p3.z; d[15]+=p3.w;
    }
    const float inv = 1.0f / NN;
    float sumsq = 0.f;
#pragma unroll
    for (int j = 0; j < 16; ++j) { d[j] *= inv; sumsq = fmaf(d[j], d[j], sumsq); }
#pragma unroll
    for (int sh = 1; sh <= 32; sh <<= 1) sumsq += bpf(aself ^ (sh << 2), sumsq);
    if (lane == 0) atomicAdd(norm_acc, sqrtf(sumsq));

    // Delta -> s0 (row-major, stride LD2)
    {
        float4* dp = (float4*)&s0[r * LD2 + cb];
        dp[0] = make_float4(d[0],  d[1],  d[2],  d[3]);
        dp[1] = make_float4(d[4],  d[5],  d[6],  d[7]);
        dp[2] = make_float4(d[8],  d[9],  d[10], d[11]);
        dp[3] = make_float4(d[12], d[13], d[14], d[15]);
    }
    wsync();

    // expm_taylor order 5
    float outr[16];
#pragma unroll
    for (int j = 0; j < 16; ++j)
        outr[j] = ((cb + j) == r ? 1.0f : 0.0f) + d[j];
    float fac = 1.0f;
#pragma unroll 1
    for (int i = 2; i <= 5; ++i) {
        fac *= (float)i;
        float acc[16];
#pragma unroll
        for (int j = 0; j < 16; ++j) acc[j] = 0.f;
        const float* Xp = (i == 2) ? s0 : s1;
        for (int k = 0; k < DD; ++k) {
            float av = Xp[r * LD2 + k];
            const float4* Br = (const float4*)&s0[k * LD2 + cb];
            float4 b0 = Br[0], b1 = Br[1], b2 = Br[2], b3 = Br[3];
            acc[0]+=av*b0.x; acc[1]+=av*b0.y; acc[2]+=av*b0.z; acc[3]+=av*b0.w;
            acc[4]+=av*b1.x; acc[5]+=av*b1.y; acc[6]+=av*b1.z; acc[7]+=av*b1.w;
            acc[8]+=av*b2.x; acc[9]+=av*b2.y; acc[10]+=av*b2.z; acc[11]+=av*b2.w;
            acc[12]+=av*b3.x; acc[13]+=av*b3.y; acc[14]+=av*b3.z; acc[15]+=av*b3.w;
        }
        float invf = 1.0f / fac;
#pragma unroll
        for (int j = 0; j < 16; ++j) outr[j] = fmaf(acc[j], invf, outr[j]);
        wsync();
        float4* dp = (float4*)&s1[r * LD2 + cb];
        dp[0] = make_float4(acc[0],  acc[1],  acc[2],  acc[3]);
        dp[1] = make_float4(acc[4],  acc[5],  acc[6],  acc[7]);
        dp[2] = make_float4(acc[8],  acc[9],  acc[10], acc[11]);
        dp[3] = make_float4(acc[12], acc[13], acc[14], acc[15]);
        wsync();
    }
    // E -> s0; Gs -> s1
    {
        float4* dp = (float4*)&s0[r * LD2 + cb];
        dp[0] = make_float4(outr[0],  outr[1],  outr[2],  outr[3]);
        dp[1] = make_float4(outr[4],  outr[5],  outr[6],  outr[7]);
        dp[2] = make_float4(outr[8],  outr[9],  outr[10], outr[11]);
        dp[3] = make_float4(outr[12], outr[13], outr[14], outr[15]);
        const float4* Gsb = (const float4*)(Gs + b * 1024);
#pragma unroll
        for (int j4 = 0; j4 < 4; ++j4) {
            float4 v = Gsb[lane * 4 + j4];
            int e = lane * 16 + j4 * 4;
            *((float4*)&s1[(e >> 5) * LD2 + (e & 31)]) = v;
        }
    }
    wsync();
    mm32w(s1, s0, s2, lane);   // T = Gs * E
    mm32w(s2, s1, s0, lane);   // M = T * Gs

    // enforce_spd via one-sided Jacobi: extract col with symmetrize + jitter
    float a[16];
    {
#pragma unroll
        for (int i = 0; i < 16; ++i) {
            int row = 16 * h + i;
            float own = s0[c * LD2 + row];
            float v = 0.5f * (s0[row * LD2 + c] + own);
            if (row == c) v = own + JIT;
            a[i] = v;
        }
    }
    jac1(a, aself, a32, c, 10, 1e-12f);
    float gs2 = 0.f;
#pragma unroll
    for (int i = 0; i < 16; ++i) gs2 = fmaf(a[i], a[i], gs2);
    gs2 += bpf(a32, gs2);
    float l = __builtin_amdgcn_sqrtf(gs2);
    float coef = fmaxf(l, JIT) * __builtin_amdgcn_rcpf(gs2);   // clip(lam)/lam^2
    wsync();
    {
        float4* wp = (float4*)&s1[c * LD2 + 16 * h];
        wp[0] = make_float4(a[0],  a[1],  a[2],  a[3]);
        wp[1] = make_float4(a[4],  a[5],  a[6],  a[7]);
        wp[2] = make_float4(a[8],  a[9],  a[10], a[11]);
        wp[3] = make_float4(a[12], a[13], a[14], a[15]);
        if (h == 0) sc[c] = coef;
    }
    wsync();
    float g[16];
#pragma unroll
    for (int j = 0; j < 16; ++j) g[j] = 0.f;
    for (int k = 0; k < DD; ++k) {
        float t1 = s1[k * LD2 + r] * sc[k];
        const float4* Wc = (const float4*)&s1[k * LD2 + cb];
        float4 w0 = Wc[0], w1 = Wc[1], w2 = Wc[2], w3 = Wc[3];
        g[0]+=t1*w0.x; g[1]+=t1*w0.y; g[2]+=t1*w0.z; g[3]+=t1*w0.w;
        g[4]+=t1*w1.x; g[5]+=t1*w1.y; g[6]+=t1*w1.z; g[7]+=t1*w1.w;
        g[8]+=t1*w2.x; g[9]+=t1*w2.y; g[10]+=t1*w2.z; g[11]+=t1*w2.w;
        g[12]+=t1*w3.x; g[13]+=t1*w3.y; g[14]+=t1*w3.z; g[15]+=t1*w3.w;
    }
    float4* Gb = (float4*)(G + b * 1024 + lane * 16);
#pragma unroll
    for (int j4 = 0; j4 < 4; ++j4)
        Gb[j4] = make_float4(g[4*j4], g[4*j4+1], g[4*j4+2], g[4*j4+3]);
}

__global__ void k4_check(const float* __restrict__ norm_acc, int* __restrict__ done) {
    if (threadIdx.x == 0) {
        if (*norm_acc * (1.0f / BB) < TOLF) *done = 1;
    }
}

__global__ __launch_bounds__(256) void k5_out(const float* __restrict__ G, float* __restrict__ out) {
    int i = blockIdx.x * 256 + threadIdx.x;
    out[i] = G[i];
}

extern "C" void kernel_launch(void* const* d_in, const int* in_sizes, int n_in,
                              void* d_out, int out_size, void* d_ws, size_t ws_size,
                              hipStream_t stream) {
    const float* X = (const float*)d_in[0];
    float* ws = (float*)d_ws;
    float* G     = ws;                        // 65536
    float* Gs    = ws + 65536;                // 65536
    float* Gis   = ws + 2 * 65536;            // 65536
    float* Part  = ws + 3 * 65536;            // 1024 blocks * 1024 = 1048576
    float* norm_acc = ws + 3 * 65536 + 1048576;
    int*   done  = (int*)(norm_acc + 1);

    k0_zero<<<64, 256, 0, stream>>>(G, done, norm_acc);
    k0_mean<<<512, 256, 0, stream>>>(X, G);
    for (int it = 0; it < MAXIT; ++it) {
        k1_eig_g<<<64, 64, 0, stream>>>(G, Gs, Gis, norm_acc, done);
        k2_log_acc<<<1024, 256, 0, stream>>>(X, Gis, Part, done);
        k3_update<<<64, 64, 0, stream>>>(G, Gs, Part, norm_acc, done);
        k4_check<<<1, 64, 0, stream>>>(norm_acc, done);
    }
    k5_out<<<256, 256, 0, stream>>>(G, (float*)d_out);
}